// Round 1
// baseline (16040.556 us; speedup 1.0000x reference)
//
#include <hip/hip_runtime.h>

#define NN 1000000
#define NE 32000000

// ---- dtype detector: writes flag=1 if edge_index is int64, 0 if int32 ----
// int64 little-endian values < 2^31 have all-zero high words (odd int32 words).
__global__ void detect_kernel(const int* __restrict__ ei, int* __restrict__ flag) {
    __shared__ int nz;
    if (threadIdx.x == 0) nz = 0;
    __syncthreads();
    // inspect odd 32-bit words among the first 512 words of row 0
    int w = ei[2 * threadIdx.x + 1];
    if (w != 0) atomicAdd(&nz, 1);
    __syncthreads();
    if (threadIdx.x == 0) *flag = (nz == 0) ? 1 : 0;
}

// ---- degree histogram over dst (includes implicit +1 self-loop later) ----
__global__ void deg_kernel(const int* __restrict__ ei, int* __restrict__ deg,
                           const int* __restrict__ flagp, int nE) {
    int i = blockIdx.x * blockDim.x + threadIdx.x;
    if (i >= nE) return;
    int shift = *flagp;                       // 0: int32, 1: int64 (read low word)
    const int* dstp = ei + ((size_t)nE << shift);
    int d = dstp[(size_t)i << shift];
    atomicAdd(&deg[d], 1);
}

// ---- dinv[i] = rsqrt(deg[i] + 1)  (in place: int -> float) ----
__global__ void dinv_kernel(void* __restrict__ buf, int nN) {
    int i = blockIdx.x * blockDim.x + threadIdx.x;
    if (i >= nN) return;
    int d = ((const int*)buf)[i] + 1;         // +1 self-loop
    ((float*)buf)[i] = rsqrtf((float)d);
}

// ---- layer 1: out1[d*8+j] += (x[s] @ W1)[j] * dinv[s]*dinv[d] over E+N ----
__global__ void l1_kernel(const int* __restrict__ ei, const float2* __restrict__ x,
                          const float* __restrict__ dinv, const float* __restrict__ W1,
                          float* __restrict__ out1, const int* __restrict__ flagp,
                          int nE, int nN) {
    int i = blockIdx.x * blockDim.x + threadIdx.x;
    if (i >= nE + nN) return;
    int shift = *flagp;
    int s, d;
    if (i < nE) {
        const int* srcp = ei;
        const int* dstp = ei + ((size_t)nE << shift);
        s = srcp[(size_t)i << shift];
        d = dstp[(size_t)i << shift];
    } else {
        s = d = i - nE;                       // self-loop
    }
    float nrm = dinv[s] * dinv[d];
    float2 xs = x[s];
    float c0 = xs.x * nrm, c1 = xs.y * nrm;
#pragma unroll
    for (int j = 0; j < 8; ++j) {
        float h = fmaf(c0, W1[j], c1 * W1[8 + j]);   // W1 is (2,8) row-major
        unsafeAtomicAdd(&out1[(size_t)d * 8 + j], h);
    }
}

// ---- per-node: h2[i] = relu(out1[i]+b1) @ W2 ----
__global__ void h2_kernel(const float4* __restrict__ out1, const float* __restrict__ b1,
                          const float* __restrict__ W2, float* __restrict__ h2, int nN) {
    int i = blockIdx.x * blockDim.x + threadIdx.x;
    if (i >= nN) return;
    float4 a = out1[(size_t)i * 2];
    float4 b = out1[(size_t)i * 2 + 1];
    float acc = 0.f;
    acc += fmaxf(a.x + b1[0], 0.f) * W2[0];
    acc += fmaxf(a.y + b1[1], 0.f) * W2[1];
    acc += fmaxf(a.z + b1[2], 0.f) * W2[2];
    acc += fmaxf(a.w + b1[3], 0.f) * W2[3];
    acc += fmaxf(b.x + b1[4], 0.f) * W2[4];
    acc += fmaxf(b.y + b1[5], 0.f) * W2[5];
    acc += fmaxf(b.z + b1[6], 0.f) * W2[6];
    acc += fmaxf(b.w + b1[7], 0.f) * W2[7];
    h2[i] = acc;
}

// ---- layer 2: out2[d] += h2[s] * dinv[s]*dinv[d] over E+N ----
__global__ void l2_kernel(const int* __restrict__ ei, const float* __restrict__ dinv,
                          const float* __restrict__ h2, float* __restrict__ out2,
                          const int* __restrict__ flagp, int nE, int nN) {
    int i = blockIdx.x * blockDim.x + threadIdx.x;
    if (i >= nE + nN) return;
    int shift = *flagp;
    int s, d;
    if (i < nE) {
        const int* srcp = ei;
        const int* dstp = ei + ((size_t)nE << shift);
        s = srcp[(size_t)i << shift];
        d = dstp[(size_t)i << shift];
    } else {
        s = d = i - nE;
    }
    unsafeAtomicAdd(&out2[d], h2[s] * dinv[s] * dinv[d]);
}

// ---- final: out[i] = sigmoid(out2[i] + b2) ----
__global__ void fin_kernel(const float* __restrict__ out2, const float* __restrict__ b2,
                           float* __restrict__ out, int nN) {
    int i = blockIdx.x * blockDim.x + threadIdx.x;
    if (i >= nN) return;
    float z = out2[i] + b2[0];
    out[i] = 1.f / (1.f + expf(-z));
}

extern "C" void kernel_launch(void* const* d_in, const int* in_sizes, int n_in,
                              void* d_out, int out_size, void* d_ws, size_t ws_size,
                              hipStream_t stream) {
    const float* x  = (const float*)d_in[0];
    const int*   ei = (const int*)d_in[1];
    const float* W1 = (const float*)d_in[2];
    const float* b1 = (const float*)d_in[3];
    const float* W2 = (const float*)d_in[4];
    const float* b2 = (const float*)d_in[5];
    float* out = (float*)d_out;

    const int nE = NE, nN = NN;

    // workspace layout (bytes): [0,4M) deg/dinv  [4M,36M) out1  [36M,40M) out2
    //                           [40M,44M) h2     [44M,+4) flag
    char* ws = (char*)d_ws;
    float* dinv = (float*)ws;
    float* out1 = (float*)(ws + 4000000);
    float* out2 = (float*)(ws + 36000000);
    float* h2   = (float*)(ws + 40000000);
    int*   flag = (int*)(ws + 44000000);

    // zero deg + out1 + out2 (first 40 MB) — harness poisons ws with 0xAA
    hipMemsetAsync(d_ws, 0, 40000000, stream);

    const int bs = 256;
    detect_kernel<<<1, 256, 0, stream>>>(ei, flag);
    deg_kernel<<<(nE + bs - 1) / bs, bs, 0, stream>>>(ei, (int*)dinv, flag, nE);
    dinv_kernel<<<(nN + bs - 1) / bs, bs, 0, stream>>>(dinv, nN);
    int tot = nE + nN;
    l1_kernel<<<(tot + bs - 1) / bs, bs, 0, stream>>>(ei, (const float2*)x, dinv, W1,
                                                      out1, flag, nE, nN);
    h2_kernel<<<(nN + bs - 1) / bs, bs, 0, stream>>>((const float4*)out1, b1, W2, h2, nN);
    l2_kernel<<<(tot + bs - 1) / bs, bs, 0, stream>>>(ei, dinv, h2, out2, flag, nE, nN);
    fin_kernel<<<(nN + bs - 1) / bs, bs, 0, stream>>>(out2, b2, out, nN);
}

// Round 2
// 4989.015 us; speedup vs baseline: 3.2152x; 3.2152x over previous
//
#include <hip/hip_runtime.h>

#define NN 1000000
#define NE 32000000
#define SCAN_B 256
#define NB1 ((NN + SCAN_B - 1) / SCAN_B)   // 3907 scan blocks

// ---- dtype detector: flag=1 if edge_index is int64, 0 if int32 ----
// int64 little-endian values < 2^31 have all-zero high (odd) words.
__global__ void detect_kernel(const int* __restrict__ ei, int* __restrict__ flag) {
    __shared__ int nz;
    if (threadIdx.x == 0) nz = 0;
    __syncthreads();
    int w = ei[2 * threadIdx.x + 1];
    if (w != 0) atomicAdd(&nz, 1);
    __syncthreads();
    if (threadIdx.x == 0) *flag = (nz == 0) ? 1 : 0;
}

__device__ __forceinline__ void load_edge(const int* __restrict__ ei, int shift,
                                          int nE, int i, int& s, int& d) {
    s = ei[(size_t)i << shift];
    d = ei[((size_t)nE << shift) + ((size_t)i << shift)];
}

// ---- degree histogram over dst ----
__global__ void deg_kernel(const int* __restrict__ ei, int* __restrict__ deg,
                           const int* __restrict__ flagp, int nE) {
    int i = blockIdx.x * blockDim.x + threadIdx.x;
    if (i >= nE) return;
    int shift = *flagp;
    int d = ei[((size_t)nE << shift) + ((size_t)i << shift)];
    atomicAdd(&deg[d], 1);
}

// ---- per node: dinv = rsqrt(deg+1); xd = x * dinv ----
__global__ void prep_kernel(const int* __restrict__ deg, const float2* __restrict__ x,
                            float* __restrict__ dinv, float2* __restrict__ xd, int nN) {
    int i = blockIdx.x * blockDim.x + threadIdx.x;
    if (i >= nN) return;
    float di = rsqrtf((float)(deg[i] + 1));
    dinv[i] = di;
    float2 v = x[i];
    xd[i] = make_float2(v.x * di, v.y * di);
}

// ---- scan stage 1: per-block exclusive scan of deg -> off (partial), block sums ----
__global__ void scan1_kernel(const int* __restrict__ deg, int* __restrict__ off,
                             int* __restrict__ bsum, int nN) {
    __shared__ int sm[SCAN_B];
    int t = threadIdx.x;
    int i = blockIdx.x * SCAN_B + t;
    int v = (i < nN) ? deg[i] : 0;
    sm[t] = v;
    __syncthreads();
    for (int o = 1; o < SCAN_B; o <<= 1) {
        int a = (t >= o) ? sm[t - o] : 0;
        __syncthreads();
        sm[t] += a;
        __syncthreads();
    }
    if (i < nN) off[i] = sm[t] - v;          // exclusive within block
    if (t == SCAN_B - 1) bsum[blockIdx.x] = sm[t];
}

// ---- scan stage 2: exclusive scan of block sums (single 1024-thread block) ----
__global__ void scan2_kernel(int* __restrict__ bsum, int nb) {
    __shared__ int sm[1024];
    int t = threadIdx.x;
    int base = t * 4;
    int v[4];
    int s = 0;
#pragma unroll
    for (int j = 0; j < 4; ++j) {
        v[j] = (base + j < nb) ? bsum[base + j] : 0;
        s += v[j];
    }
    sm[t] = s;
    __syncthreads();
    for (int o = 1; o < 1024; o <<= 1) {
        int a = (t >= o) ? sm[t - o] : 0;
        __syncthreads();
        sm[t] += a;
        __syncthreads();
    }
    int run = sm[t] - s;                     // exclusive prefix for this thread's chunk
#pragma unroll
    for (int j = 0; j < 4; ++j) {
        if (base + j < nb) bsum[base + j] = run;
        run += v[j];
    }
}

// ---- scan stage 3: add block offsets; copy cursors; set off[nN] ----
__global__ void scan3_kernel(int* __restrict__ off, int* __restrict__ pos,
                             const int* __restrict__ bsum, int nN, int nE) {
    int i = blockIdx.x * blockDim.x + threadIdx.x;
    if (i < nN) {
        int o = off[i] + bsum[i >> 8];       // 256 = SCAN_B
        off[i] = o;
        pos[i] = o;
    }
    if (i == 0) off[nN] = nE;
}

// ---- scatter edges into CSR order by dst ----
__global__ void scatter_kernel(const int* __restrict__ ei, int* __restrict__ pos,
                               int* __restrict__ ssrc, const int* __restrict__ flagp, int nE) {
    int i = blockIdx.x * blockDim.x + threadIdx.x;
    if (i >= nE) return;
    int shift = *flagp;
    int s, d;
    load_edge(ei, shift, nE, i, s, d);
    int idx = atomicAdd(&pos[d], 1);
    ssrc[idx] = s;
}

// ---- layer1+layer2-prep fused gather (atomic-free):
//      agg = dd*(xd[d]*dd + sum_in xd[s]);  hd[d] = (relu(agg@W1+b1)@W2)*dd ----
__global__ void l1g_kernel(const int* __restrict__ off, const int* __restrict__ ssrc,
                           const float* __restrict__ dinv, const float2* __restrict__ xd,
                           const float* __restrict__ W1, const float* __restrict__ b1,
                           const float* __restrict__ W2, float* __restrict__ hd, int nN) {
    int d = blockIdx.x * blockDim.x + threadIdx.x;
    if (d >= nN) return;
    float dd = dinv[d];
    float2 xs = xd[d];
    float ax = xs.x * dd, ay = xs.y * dd;    // self-loop: x[d]*dd*dd -> xd[d]*dd
    int k0 = off[d], k1 = off[d + 1];
    for (int k = k0; k < k1; ++k) {
        int s = ssrc[k];
        float2 v = xd[s];
        ax += v.x;
        ay += v.y;
    }
    ax *= dd;
    ay *= dd;
    float acc = 0.f;
#pragma unroll
    for (int j = 0; j < 8; ++j) {
        float h = fmaf(ax, W1[j], fmaf(ay, W1[8 + j], b1[j]));
        acc = fmaf(fmaxf(h, 0.f), W2[j], acc);
    }
    hd[d] = acc * dd;                        // hd = h2 * dinv
}

// ---- layer2 gather + sigmoid: out[d] = sig(dd*(hd[d] + sum_in hd[s]) + b2) ----
__global__ void l2g_kernel(const int* __restrict__ off, const int* __restrict__ ssrc,
                           const float* __restrict__ dinv, const float* __restrict__ hd,
                           const float* __restrict__ b2, float* __restrict__ out, int nN) {
    int d = blockIdx.x * blockDim.x + threadIdx.x;
    if (d >= nN) return;
    float dd = dinv[d];
    float a = hd[d];                         // self-loop
    int k0 = off[d], k1 = off[d + 1];
    for (int k = k0; k < k1; ++k) a += hd[ssrc[k]];
    float z = fmaf(dd, a, b2[0]);
    out[d] = 1.f / (1.f + expf(-z));
}

// ================= fallback (small-workspace) atomic path =================

// layer1 aggregate (2 atomics/edge, real edges only): agg[d] += xd[s]
__global__ void l1a_kernel(const int* __restrict__ ei, const float2* __restrict__ xd,
                           float* __restrict__ agg, const int* __restrict__ flagp, int nE) {
    int i = blockIdx.x * blockDim.x + threadIdx.x;
    if (i >= nE) return;
    int shift = *flagp;
    int s, d;
    load_edge(ei, shift, nE, i, s, d);
    float2 v = xd[s];
    unsafeAtomicAdd(&agg[(size_t)d * 2], v.x);
    unsafeAtomicAdd(&agg[(size_t)d * 2 + 1], v.y);
}

// per-node: add self term, apply W1/b1/relu/W2 -> hd
__global__ void h2f_kernel(const float2* __restrict__ agg, const float2* __restrict__ xd,
                           const float* __restrict__ dinv, const float* __restrict__ W1,
                           const float* __restrict__ b1, const float* __restrict__ W2,
                           float* __restrict__ hd, int nN) {
    int d = blockIdx.x * blockDim.x + threadIdx.x;
    if (d >= nN) return;
    float dd = dinv[d];
    float2 a = agg[d];
    float2 xs = xd[d];
    float ax = (a.x + xs.x * dd) * dd;
    float ay = (a.y + xs.y * dd) * dd;
    float acc = 0.f;
#pragma unroll
    for (int j = 0; j < 8; ++j) {
        float h = fmaf(ax, W1[j], fmaf(ay, W1[8 + j], b1[j]));
        acc = fmaf(fmaxf(h, 0.f), W2[j], acc);
    }
    hd[d] = acc * dd;
}

// layer2 aggregate (1 atomic/edge): out2[d] += hd[s]
__global__ void l2a_kernel(const int* __restrict__ ei, const float* __restrict__ hd,
                           float* __restrict__ out2, const int* __restrict__ flagp, int nE) {
    int i = blockIdx.x * blockDim.x + threadIdx.x;
    if (i >= nE) return;
    int shift = *flagp;
    int s, d;
    load_edge(ei, shift, nE, i, s, d);
    unsafeAtomicAdd(&out2[d], hd[s]);
}

__global__ void finf_kernel(const float* __restrict__ out2, const float* __restrict__ hd,
                            const float* __restrict__ dinv, const float* __restrict__ b2,
                            float* __restrict__ out, int nN) {
    int d = blockIdx.x * blockDim.x + threadIdx.x;
    if (d >= nN) return;
    float z = fmaf(dinv[d], out2[d] + hd[d], b2[0]);
    out[d] = 1.f / (1.f + expf(-z));
}

extern "C" void kernel_launch(void* const* d_in, const int* in_sizes, int n_in,
                              void* d_out, int out_size, void* d_ws, size_t ws_size,
                              hipStream_t stream) {
    const float* x  = (const float*)d_in[0];
    const int*   ei = (const int*)d_in[1];
    const float* W1 = (const float*)d_in[2];
    const float* b1 = (const float*)d_in[3];
    const float* W2 = (const float*)d_in[4];
    const float* b2 = (const float*)d_in[5];
    float* out = (float*)d_out;

    const int nE = NE, nN = NN;
    const int bs = 256;
    char* ws = (char*)d_ws;
    const size_t MiB = 1 << 20;

    const size_t csr_need = 32 * MiB + (size_t)nE * 4;   // ssrc @32MiB + 128MB

    if (ws_size >= csr_need) {
        // CSR path layout (MiB offsets):
        // deg@0  off@4 (NN+1)  pos@8  dinv@12  xd@16..24  hd@24  bsum@28  flag@28+64K  ssrc@32
        int*    deg  = (int*)ws;
        int*    off  = (int*)(ws + 4 * MiB);
        int*    pos  = (int*)(ws + 8 * MiB);
        float*  dinv = (float*)(ws + 12 * MiB);
        float2* xd   = (float2*)(ws + 16 * MiB);
        float*  hd   = (float*)(ws + 24 * MiB);
        int*    bsum = (int*)(ws + 28 * MiB);
        int*    flag = (int*)(ws + 28 * MiB + 65536);
        int*    ssrc = (int*)(ws + 32 * MiB);

        hipMemsetAsync(deg, 0, (size_t)nN * 4, stream);  // only deg needs zeros

        detect_kernel<<<1, 256, 0, stream>>>(ei, flag);
        deg_kernel<<<(nE + bs - 1) / bs, bs, 0, stream>>>(ei, deg, flag, nE);
        prep_kernel<<<(nN + bs - 1) / bs, bs, 0, stream>>>(deg, (const float2*)x, dinv, xd, nN);
        scan1_kernel<<<NB1, SCAN_B, 0, stream>>>(deg, off, bsum, nN);
        scan2_kernel<<<1, 1024, 0, stream>>>(bsum, NB1);
        scan3_kernel<<<(nN + bs - 1) / bs, bs, 0, stream>>>(off, pos, bsum, nN, nE);
        scatter_kernel<<<(nE + bs - 1) / bs, bs, 0, stream>>>(ei, pos, ssrc, flag, nE);
        l1g_kernel<<<(nN + bs - 1) / bs, bs, 0, stream>>>(off, ssrc, dinv, xd, W1, b1, W2, hd, nN);
        l2g_kernel<<<(nN + bs - 1) / bs, bs, 0, stream>>>(off, ssrc, dinv, hd, b2, out, nN);
    } else {
        // fallback layout: deg@0  agg@4..12  out2@12  dinv@16  xd@20..28  hd@28  flag@32MiB
        int*    deg  = (int*)ws;
        float*  agg  = (float*)(ws + 4 * MiB);
        float*  out2 = (float*)(ws + 12 * MiB);
        float*  dinv = (float*)(ws + 16 * MiB);
        float2* xd   = (float2*)(ws + 20 * MiB);
        float*  hd   = (float*)(ws + 28 * MiB);
        int*    flag = (int*)(ws + 32 * MiB);

        hipMemsetAsync(ws, 0, 16 * MiB, stream);         // deg + agg + out2

        detect_kernel<<<1, 256, 0, stream>>>(ei, flag);
        deg_kernel<<<(nE + bs - 1) / bs, bs, 0, stream>>>(ei, deg, flag, nE);
        prep_kernel<<<(nN + bs - 1) / bs, bs, 0, stream>>>(deg, (const float2*)x, dinv, xd, nN);
        l1a_kernel<<<(nE + bs - 1) / bs, bs, 0, stream>>>(ei, xd, agg, flag, nE);
        h2f_kernel<<<(nN + bs - 1) / bs, bs, 0, stream>>>((const float2*)agg, xd, dinv,
                                                          W1, b1, W2, hd, nN);
        l2a_kernel<<<(nE + bs - 1) / bs, bs, 0, stream>>>(ei, hd, out2, flag, nE);
        finf_kernel<<<(nN + bs - 1) / bs, bs, 0, stream>>>(out2, hd, dinv, b2, out, nN);
    }
}

// Round 3
// 1715.921 us; speedup vs baseline: 9.3481x; 2.9075x over previous
//
#include <hip/hip_runtime.h>

#define NN 1000000
#define NE 32000000
#define SCAN_B 256

// bucket decomposition: bucket = d >> 10, 1024 nodes per bucket
#define BK_SH 10
#define BK_SZ 1024
#define NB 977                       // ceil(NN / BK_SZ)
#define GAB 1024                     // edge-chunk blocks for passes A and C
#define CHUNK ((NE + GAB - 1) / GAB) // 31250 edges per chunk
#define NL (NB * GAB)                // hist length = 1000448
#define NBS (NL / SCAN_B)            // 3908 scan blocks (exact)

// ---- dtype detector: flag=1 if edge_index is int64, 0 if int32 ----
// int64 little-endian values < 2^31 have all-zero high (odd) words.
__global__ void detect_kernel(const int* __restrict__ ei, int* __restrict__ flag) {
    __shared__ int nz;
    if (threadIdx.x == 0) nz = 0;
    __syncthreads();
    int w = ei[2 * threadIdx.x + 1];
    if (w != 0) atomicAdd(&nz, 1);
    __syncthreads();
    if (threadIdx.x == 0) *flag = (nz == 0) ? 1 : 0;
}

// ---- pass A: per-block LDS histogram over buckets -> hist[b*GAB + g] ----
__global__ void passA_kernel(const int* __restrict__ ei, int* __restrict__ hist,
                             const int* __restrict__ flagp, int nE) {
    __shared__ int h[NB];
    int t = threadIdx.x;
    for (int b = t; b < NB; b += 256) h[b] = 0;
    __syncthreads();
    int shift = *flagp;
    size_t dbase = (size_t)nE << shift;
    int start = blockIdx.x * CHUNK;
    int end = min(start + CHUNK, nE);
    for (int i = start + t; i < end; i += 256) {
        int d = ei[dbase + ((size_t)i << shift)];
        atomicAdd(&h[d >> BK_SH], 1);
    }
    __syncthreads();
    for (int b = t; b < NB; b += 256)
        hist[(size_t)b * GAB + blockIdx.x] = h[b];
}

// ---- scan stage 1: per-block exclusive scan (in-place ok), block sums ----
__global__ void scan1_kernel(int* __restrict__ data, int* __restrict__ bsum, int n) {
    __shared__ int sm[SCAN_B];
    int t = threadIdx.x;
    int i = blockIdx.x * SCAN_B + t;
    int v = (i < n) ? data[i] : 0;
    sm[t] = v;
    __syncthreads();
    for (int o = 1; o < SCAN_B; o <<= 1) {
        int a = (t >= o) ? sm[t - o] : 0;
        __syncthreads();
        sm[t] += a;
        __syncthreads();
    }
    if (i < n) data[i] = sm[t] - v;
    if (t == SCAN_B - 1) bsum[blockIdx.x] = sm[t];
}

// ---- scan stage 2: exclusive scan of block sums (1 block, up to 4096) ----
__global__ void scan2_kernel(int* __restrict__ bsum, int nb) {
    __shared__ int sm[1024];
    int t = threadIdx.x;
    int base = t * 4;
    int v[4];
    int s = 0;
#pragma unroll
    for (int j = 0; j < 4; ++j) {
        v[j] = (base + j < nb) ? bsum[base + j] : 0;
        s += v[j];
    }
    sm[t] = s;
    __syncthreads();
    for (int o = 1; o < 1024; o <<= 1) {
        int a = (t >= o) ? sm[t - o] : 0;
        __syncthreads();
        sm[t] += a;
        __syncthreads();
    }
    int run = sm[t] - s;
#pragma unroll
    for (int j = 0; j < 4; ++j) {
        if (base + j < nb) bsum[base + j] = run;
        run += v[j];
    }
}

// ---- scan stage 3: add block offsets back ----
__global__ void scan3_kernel(int* __restrict__ data, const int* __restrict__ bsum, int n) {
    int i = blockIdx.x * blockDim.x + threadIdx.x;
    if (i < n) data[i] += bsum[i >> 8];
}

// ---- pass C: scatter packed edges into bucket-contiguous regions ----
// pairs[idx] = s | (d_local << 20)   (s < 2^20, d_local < 2^10)
__global__ void passC_kernel(const int* __restrict__ ei, const int* __restrict__ hist,
                             unsigned int* __restrict__ pairs,
                             const int* __restrict__ flagp, int nE) {
    __shared__ int cur[NB];
    int t = threadIdx.x;
    for (int b = t; b < NB; b += 256)
        cur[b] = hist[(size_t)b * GAB + blockIdx.x];
    __syncthreads();
    int shift = *flagp;
    size_t dbase = (size_t)nE << shift;
    int start = blockIdx.x * CHUNK;
    int end = min(start + CHUNK, nE);
    for (int i = start + t; i < end; i += 256) {
        int s = ei[(size_t)i << shift];
        int d = ei[dbase + ((size_t)i << shift)];
        int idx = atomicAdd(&cur[d >> BK_SH], 1);
        pairs[idx] = (unsigned int)s | ((unsigned int)(d & (BK_SZ - 1)) << 20);
    }
}

// ---- pass D0: per-bucket degree count -> dinv, xd = x * dinv ----
__global__ void passD0_kernel(const unsigned int* __restrict__ pairs,
                              const int* __restrict__ hist, const float2* __restrict__ x,
                              float* __restrict__ dinv, float2* __restrict__ xd,
                              int nE, int nN) {
    __shared__ int degl[BK_SZ];
    int t = threadIdx.x;
    int b = blockIdx.x;
    for (int j = t; j < BK_SZ; j += 256) degl[j] = 0;
    __syncthreads();
    int base = hist[(size_t)b * GAB];
    int endp = (b + 1 < NB) ? hist[(size_t)(b + 1) * GAB] : nE;
    for (int k = base + t; k < endp; k += 256)
        atomicAdd(&degl[pairs[k] >> 20], 1);
    __syncthreads();
    for (int j = t; j < BK_SZ; j += 256) {
        int nid = (b << BK_SH) + j;
        if (nid < nN) {
            float di = rsqrtf((float)(degl[j] + 1));   // +1 self-loop
            dinv[nid] = di;
            float2 v = x[nid];
            xd[nid] = make_float2(v.x * di, v.y * di);
        }
    }
}

// ---- pass L1: per-bucket aggregate xd, fuse W1/b1/relu/W2 -> hd = h2*dinv ----
__global__ void passL1_kernel(const unsigned int* __restrict__ pairs,
                              const int* __restrict__ hist, const float* __restrict__ dinv,
                              const float2* __restrict__ xd, const float* __restrict__ W1,
                              const float* __restrict__ b1, const float* __restrict__ W2,
                              float* __restrict__ hd, int nE, int nN) {
    __shared__ float ax[BK_SZ];
    __shared__ float ay[BK_SZ];
    int t = threadIdx.x;
    int b = blockIdx.x;
    for (int j = t; j < BK_SZ; j += 256) { ax[j] = 0.f; ay[j] = 0.f; }
    __syncthreads();
    int base = hist[(size_t)b * GAB];
    int endp = (b + 1 < NB) ? hist[(size_t)(b + 1) * GAB] : nE;
    for (int k = base + t; k < endp; k += 256) {
        unsigned int p = pairs[k];
        int s = p & 0xFFFFF;
        int dl = p >> 20;
        float2 v = xd[s];
        atomicAdd(&ax[dl], v.x);
        atomicAdd(&ay[dl], v.y);
    }
    __syncthreads();
    for (int j = t; j < BK_SZ; j += 256) {
        int nid = (b << BK_SH) + j;
        if (nid < nN) {
            float dd = dinv[nid];
            float2 xs = xd[nid];
            float AX = (ax[j] + xs.x * dd) * dd;       // self-loop: xd*dd
            float AY = (ay[j] + xs.y * dd) * dd;
            float acc = 0.f;
#pragma unroll
            for (int c = 0; c < 8; ++c) {
                float h = fmaf(AX, W1[c], fmaf(AY, W1[8 + c], b1[c]));
                acc = fmaf(fmaxf(h, 0.f), W2[c], acc);
            }
            hd[nid] = acc * dd;                        // hd = h2 * dinv
        }
    }
}

// ---- pass L2: per-bucket aggregate hd, fuse sigmoid -> out ----
__global__ void passL2_kernel(const unsigned int* __restrict__ pairs,
                              const int* __restrict__ hist, const float* __restrict__ dinv,
                              const float* __restrict__ hd, const float* __restrict__ b2,
                              float* __restrict__ out, int nE, int nN) {
    __shared__ float ag[BK_SZ];
    int t = threadIdx.x;
    int b = blockIdx.x;
    for (int j = t; j < BK_SZ; j += 256) ag[j] = 0.f;
    __syncthreads();
    int base = hist[(size_t)b * GAB];
    int endp = (b + 1 < NB) ? hist[(size_t)(b + 1) * GAB] : nE;
    for (int k = base + t; k < endp; k += 256) {
        unsigned int p = pairs[k];
        atomicAdd(&ag[p >> 20], hd[p & 0xFFFFF]);
    }
    __syncthreads();
    for (int j = t; j < BK_SZ; j += 256) {
        int nid = (b << BK_SH) + j;
        if (nid < nN) {
            float z = fmaf(dinv[nid], ag[j] + hd[nid], b2[0]);
            out[nid] = 1.f / (1.f + expf(-z));
        }
    }
}

// ================= fallback (small-workspace) atomic path =================

__global__ void deg_kernel(const int* __restrict__ ei, int* __restrict__ deg,
                           const int* __restrict__ flagp, int nE) {
    int i = blockIdx.x * blockDim.x + threadIdx.x;
    if (i >= nE) return;
    int shift = *flagp;
    int d = ei[((size_t)nE << shift) + ((size_t)i << shift)];
    atomicAdd(&deg[d], 1);
}

__global__ void prep_kernel(const int* __restrict__ deg, const float2* __restrict__ x,
                            float* __restrict__ dinv, float2* __restrict__ xd, int nN) {
    int i = blockIdx.x * blockDim.x + threadIdx.x;
    if (i >= nN) return;
    float di = rsqrtf((float)(deg[i] + 1));
    dinv[i] = di;
    float2 v = x[i];
    xd[i] = make_float2(v.x * di, v.y * di);
}

__device__ __forceinline__ void load_edge(const int* __restrict__ ei, int shift,
                                          int nE, int i, int& s, int& d) {
    s = ei[(size_t)i << shift];
    d = ei[((size_t)nE << shift) + ((size_t)i << shift)];
}

__global__ void l1a_kernel(const int* __restrict__ ei, const float2* __restrict__ xd,
                           float* __restrict__ agg, const int* __restrict__ flagp, int nE) {
    int i = blockIdx.x * blockDim.x + threadIdx.x;
    if (i >= nE) return;
    int shift = *flagp;
    int s, d;
    load_edge(ei, shift, nE, i, s, d);
    float2 v = xd[s];
    unsafeAtomicAdd(&agg[(size_t)d * 2], v.x);
    unsafeAtomicAdd(&agg[(size_t)d * 2 + 1], v.y);
}

__global__ void h2f_kernel(const float2* __restrict__ agg, const float2* __restrict__ xd,
                           const float* __restrict__ dinv, const float* __restrict__ W1,
                           const float* __restrict__ b1, const float* __restrict__ W2,
                           float* __restrict__ hd, int nN) {
    int d = blockIdx.x * blockDim.x + threadIdx.x;
    if (d >= nN) return;
    float dd = dinv[d];
    float2 a = agg[d];
    float2 xs = xd[d];
    float ax = (a.x + xs.x * dd) * dd;
    float ay = (a.y + xs.y * dd) * dd;
    float acc = 0.f;
#pragma unroll
    for (int j = 0; j < 8; ++j) {
        float h = fmaf(ax, W1[j], fmaf(ay, W1[8 + j], b1[j]));
        acc = fmaf(fmaxf(h, 0.f), W2[j], acc);
    }
    hd[d] = acc * dd;
}

__global__ void l2a_kernel(const int* __restrict__ ei, const float* __restrict__ hd,
                           float* __restrict__ out2, const int* __restrict__ flagp, int nE) {
    int i = blockIdx.x * blockDim.x + threadIdx.x;
    if (i >= nE) return;
    int shift = *flagp;
    int s, d;
    load_edge(ei, shift, nE, i, s, d);
    unsafeAtomicAdd(&out2[d], hd[s]);
}

__global__ void finf_kernel(const float* __restrict__ out2, const float* __restrict__ hd,
                            const float* __restrict__ dinv, const float* __restrict__ b2,
                            float* __restrict__ out, int nN) {
    int d = blockIdx.x * blockDim.x + threadIdx.x;
    if (d >= nN) return;
    float z = fmaf(dinv[d], out2[d] + hd[d], b2[0]);
    out[d] = 1.f / (1.f + expf(-z));
}

extern "C" void kernel_launch(void* const* d_in, const int* in_sizes, int n_in,
                              void* d_out, int out_size, void* d_ws, size_t ws_size,
                              hipStream_t stream) {
    const float* x  = (const float*)d_in[0];
    const int*   ei = (const int*)d_in[1];
    const float* W1 = (const float*)d_in[2];
    const float* b1 = (const float*)d_in[3];
    const float* W2 = (const float*)d_in[4];
    const float* b2 = (const float*)d_in[5];
    float* out = (float*)d_out;

    const int nE = NE, nN = NN;
    const int bs = 256;
    char* ws = (char*)d_ws;
    const size_t MiB = 1 << 20;

    // bucket-path layout: hist@0 (3.82MiB)  bsum@4MiB  flag@4MiB+64K
    //                     dinv@5MiB  xd@9MiB  hd@17MiB  pairs@21MiB (128MB)
    const size_t csr_need = 21 * MiB + (size_t)nE * 4;

    if (ws_size >= csr_need) {
        int*          hist  = (int*)ws;
        int*          bsum  = (int*)(ws + 4 * MiB);
        int*          flag  = (int*)(ws + 4 * MiB + 65536);
        float*        dinv  = (float*)(ws + 5 * MiB);
        float2*       xd    = (float2*)(ws + 9 * MiB);
        float*        hd    = (float*)(ws + 17 * MiB);
        unsigned int* pairs = (unsigned int*)(ws + 21 * MiB);

        detect_kernel<<<1, 256, 0, stream>>>(ei, flag);
        passA_kernel<<<GAB, 256, 0, stream>>>(ei, hist, flag, nE);
        scan1_kernel<<<NBS, SCAN_B, 0, stream>>>(hist, bsum, NL);
        scan2_kernel<<<1, 1024, 0, stream>>>(bsum, NBS);
        scan3_kernel<<<(NL + bs - 1) / bs, bs, 0, stream>>>(hist, bsum, NL);
        passC_kernel<<<GAB, 256, 0, stream>>>(ei, hist, pairs, flag, nE);
        passD0_kernel<<<NB, 256, 0, stream>>>(pairs, hist, (const float2*)x, dinv, xd, nE, nN);
        passL1_kernel<<<NB, 256, 0, stream>>>(pairs, hist, dinv, xd, W1, b1, W2, hd, nE, nN);
        passL2_kernel<<<NB, 256, 0, stream>>>(pairs, hist, dinv, hd, b2, out, nE, nN);
    } else {
        // fallback layout: deg@0  agg@4..12  out2@12  dinv@16  xd@20..28  hd@28  flag@32MiB
        int*    deg  = (int*)ws;
        float*  agg  = (float*)(ws + 4 * MiB);
        float*  out2 = (float*)(ws + 12 * MiB);
        float*  dinv = (float*)(ws + 16 * MiB);
        float2* xd   = (float2*)(ws + 20 * MiB);
        float*  hd   = (float*)(ws + 28 * MiB);
        int*    flag = (int*)(ws + 32 * MiB);

        hipMemsetAsync(ws, 0, 16 * MiB, stream);

        detect_kernel<<<1, 256, 0, stream>>>(ei, flag);
        deg_kernel<<<(nE + bs - 1) / bs, bs, 0, stream>>>(ei, deg, flag, nE);
        prep_kernel<<<(nN + bs - 1) / bs, bs, 0, stream>>>(deg, (const float2*)x, dinv, xd, nN);
        l1a_kernel<<<(nE + bs - 1) / bs, bs, 0, stream>>>(ei, xd, agg, flag, nE);
        h2f_kernel<<<(nN + bs - 1) / bs, bs, 0, stream>>>((const float2*)agg, xd, dinv,
                                                          W1, b1, W2, hd, nN);
        l2a_kernel<<<(nE + bs - 1) / bs, bs, 0, stream>>>(ei, hd, out2, flag, nE);
        finf_kernel<<<(nN + bs - 1) / bs, bs, 0, stream>>>(out2, hd, dinv, b2, out, nN);
    }
}

// Round 4
// 1310.808 us; speedup vs baseline: 12.2372x; 1.3091x over previous
//
#include <hip/hip_runtime.h>

#define NN 1000000
#define NE 32000000
#define SCAN_B 256

// bucket decomposition: bucket = d >> 12, 4096 nodes per bucket
#define BK_SH 12
#define BK_SZ 4096
#define NB 245                       // ceil(NN / BK_SZ)
#define GAB 1024                     // edge-chunk blocks for passes A and C
#define CHUNK ((NE + GAB - 1) / GAB) // 31250 edges per chunk
#define NL (NB * GAB)                // hist length = 250880 (divisible by 256)
#define NBS (NL / SCAN_B)            // 980 scan blocks (exact)

// ---- dtype detector: flag=1 if edge_index is int64, 0 if int32 ----
// int64 little-endian values < 2^31 have all-zero high (odd) words.
__global__ void detect_kernel(const int* __restrict__ ei, int* __restrict__ flag) {
    __shared__ int nz;
    if (threadIdx.x == 0) nz = 0;
    __syncthreads();
    int w = ei[2 * threadIdx.x + 1];
    if (w != 0) atomicAdd(&nz, 1);
    __syncthreads();
    if (threadIdx.x == 0) *flag = (nz == 0) ? 1 : 0;
}

// ---- pass A: per-block LDS histogram over buckets -> hist[b*GAB + g] ----
__global__ void passA_kernel(const int* __restrict__ ei, int* __restrict__ hist,
                             const int* __restrict__ flagp, int nE) {
    __shared__ int h[NB];
    int t = threadIdx.x;
    for (int b = t; b < NB; b += 512) h[b] = 0;
    __syncthreads();
    int shift = *flagp;
    size_t dbase = (size_t)nE << shift;
    int start = blockIdx.x * CHUNK;
    int end = min(start + CHUNK, nE);
    for (int i = start + t; i < end; i += 512) {
        int d = ei[dbase + ((size_t)i << shift)];
        atomicAdd(&h[d >> BK_SH], 1);
    }
    __syncthreads();
    for (int b = t; b < NB; b += 512)
        hist[(size_t)b * GAB + blockIdx.x] = h[b];
}

// ---- scan stage 1: per-block exclusive scan (in-place), block sums ----
__global__ void scan1_kernel(int* __restrict__ data, int* __restrict__ bsum, int n) {
    __shared__ int sm[SCAN_B];
    int t = threadIdx.x;
    int i = blockIdx.x * SCAN_B + t;
    int v = (i < n) ? data[i] : 0;
    sm[t] = v;
    __syncthreads();
    for (int o = 1; o < SCAN_B; o <<= 1) {
        int a = (t >= o) ? sm[t - o] : 0;
        __syncthreads();
        sm[t] += a;
        __syncthreads();
    }
    if (i < n) data[i] = sm[t] - v;
    if (t == SCAN_B - 1) bsum[blockIdx.x] = sm[t];
}

// ---- scan stage 2: exclusive scan of block sums (1 block, up to 4096) ----
__global__ void scan2_kernel(int* __restrict__ bsum, int nb) {
    __shared__ int sm[1024];
    int t = threadIdx.x;
    int base = t * 4;
    int v[4];
    int s = 0;
#pragma unroll
    for (int j = 0; j < 4; ++j) {
        v[j] = (base + j < nb) ? bsum[base + j] : 0;
        s += v[j];
    }
    sm[t] = s;
    __syncthreads();
    for (int o = 1; o < 1024; o <<= 1) {
        int a = (t >= o) ? sm[t - o] : 0;
        __syncthreads();
        sm[t] += a;
        __syncthreads();
    }
    int run = sm[t] - s;
#pragma unroll
    for (int j = 0; j < 4; ++j) {
        if (base + j < nb) bsum[base + j] = run;
        run += v[j];
    }
}

// ---- pass C: scatter packed edges into bucket-contiguous regions ----
// pairs[idx] = s | (d_local << 20)   (s < 2^20, d_local < 2^12)
__global__ void passC_kernel(const int* __restrict__ ei, const int* __restrict__ hist,
                             const int* __restrict__ bsum, unsigned int* __restrict__ pairs,
                             const int* __restrict__ flagp, int nE) {
    __shared__ int cur[NB];
    int t = threadIdx.x;
    for (int b = t; b < NB; b += 512) {
        int flat = b * GAB + blockIdx.x;
        cur[b] = hist[flat] + bsum[flat >> 8];
    }
    __syncthreads();
    int shift = *flagp;
    size_t dbase = (size_t)nE << shift;
    int start = blockIdx.x * CHUNK;
    int end = min(start + CHUNK, nE);
    for (int i = start + t; i < end; i += 512) {
        int s = ei[(size_t)i << shift];
        int d = ei[dbase + ((size_t)i << shift)];
        int idx = atomicAdd(&cur[d >> BK_SH], 1);
        pairs[idx] = (unsigned int)s | ((unsigned int)(d & (BK_SZ - 1)) << 20);
    }
}

__device__ __forceinline__ void bucket_range(const int* __restrict__ hist,
                                             const int* __restrict__ bsum,
                                             int b, int nE, int& base, int& endp) {
    int f0 = b * GAB;
    base = hist[f0] + bsum[f0 >> 8];
    if (b + 1 < NB) {
        int f1 = (b + 1) * GAB;
        endp = hist[f1] + bsum[f1 >> 8];
    } else {
        endp = nE;
    }
}

// ---- pass D0: per-bucket degree count -> dinv, xd = x * dinv ----
__global__ void passD0_kernel(const unsigned int* __restrict__ pairs,
                              const int* __restrict__ hist, const int* __restrict__ bsum,
                              const float2* __restrict__ x,
                              float* __restrict__ dinv, float2* __restrict__ xd,
                              int nE, int nN) {
    __shared__ int degl[BK_SZ];
    int t = threadIdx.x;
    int b = blockIdx.x;
    for (int j = t; j < BK_SZ; j += 1024) degl[j] = 0;
    __syncthreads();
    int base, endp;
    bucket_range(hist, bsum, b, nE, base, endp);
    for (int k = base + (t << 2); k < endp; k += 4096) {
#pragma unroll
        for (int j = 0; j < 4; ++j)
            if (k + j < endp) atomicAdd(&degl[pairs[k + j] >> 20], 1);
    }
    __syncthreads();
    for (int j = t; j < BK_SZ; j += 1024) {
        int nid = (b << BK_SH) + j;
        if (nid < nN) {
            float di = rsqrtf((float)(degl[j] + 1));   // +1 self-loop
            dinv[nid] = di;
            float2 v = x[nid];
            xd[nid] = make_float2(v.x * di, v.y * di);
        }
    }
}

// ---- pass L1: per-bucket aggregate xd, fuse W1/b1/relu/W2 -> hd = h2*dinv ----
__global__ void passL1_kernel(const unsigned int* __restrict__ pairs,
                              const int* __restrict__ hist, const int* __restrict__ bsum,
                              const float* __restrict__ dinv, const float2* __restrict__ xd,
                              const float* __restrict__ W1, const float* __restrict__ b1,
                              const float* __restrict__ W2,
                              float* __restrict__ hd, int nE, int nN) {
    __shared__ float ax[BK_SZ];
    __shared__ float ay[BK_SZ];
    int t = threadIdx.x;
    int b = blockIdx.x;
    for (int j = t; j < BK_SZ; j += 1024) { ax[j] = 0.f; ay[j] = 0.f; }
    __syncthreads();
    int base, endp;
    bucket_range(hist, bsum, b, nE, base, endp);
    for (int k = base + (t << 2); k < endp; k += 4096) {
        unsigned int p[4];
        float2 v[4];
        int lim = min(4, endp - k);
#pragma unroll
        for (int j = 0; j < 4; ++j)
            if (j < lim) p[j] = pairs[k + j];
#pragma unroll
        for (int j = 0; j < 4; ++j)
            if (j < lim) v[j] = xd[p[j] & 0xFFFFF];
#pragma unroll
        for (int j = 0; j < 4; ++j)
            if (j < lim) {
                int dl = p[j] >> 20;
                atomicAdd(&ax[dl], v[j].x);
                atomicAdd(&ay[dl], v[j].y);
            }
    }
    __syncthreads();
    for (int j = t; j < BK_SZ; j += 1024) {
        int nid = (b << BK_SH) + j;
        if (nid < nN) {
            float dd = dinv[nid];
            float2 xs = xd[nid];
            float AX = (ax[j] + xs.x * dd) * dd;       // self-loop: xd*dd
            float AY = (ay[j] + xs.y * dd) * dd;
            float acc = 0.f;
#pragma unroll
            for (int c = 0; c < 8; ++c) {
                float h = fmaf(AX, W1[c], fmaf(AY, W1[8 + c], b1[c]));
                acc = fmaf(fmaxf(h, 0.f), W2[c], acc);
            }
            hd[nid] = acc * dd;                        // hd = h2 * dinv
        }
    }
}

// ---- pass L2: per-bucket aggregate hd, fuse sigmoid -> out ----
__global__ void passL2_kernel(const unsigned int* __restrict__ pairs,
                              const int* __restrict__ hist, const int* __restrict__ bsum,
                              const float* __restrict__ dinv, const float* __restrict__ hd,
                              const float* __restrict__ b2,
                              float* __restrict__ out, int nE, int nN) {
    __shared__ float ag[BK_SZ];
    int t = threadIdx.x;
    int b = blockIdx.x;
    for (int j = t; j < BK_SZ; j += 1024) ag[j] = 0.f;
    __syncthreads();
    int base, endp;
    bucket_range(hist, bsum, b, nE, base, endp);
    for (int k = base + (t << 2); k < endp; k += 4096) {
        unsigned int p[4];
        float v[4];
        int lim = min(4, endp - k);
#pragma unroll
        for (int j = 0; j < 4; ++j)
            if (j < lim) p[j] = pairs[k + j];
#pragma unroll
        for (int j = 0; j < 4; ++j)
            if (j < lim) v[j] = hd[p[j] & 0xFFFFF];
#pragma unroll
        for (int j = 0; j < 4; ++j)
            if (j < lim) atomicAdd(&ag[p[j] >> 20], v[j]);
    }
    __syncthreads();
    for (int j = t; j < BK_SZ; j += 1024) {
        int nid = (b << BK_SH) + j;
        if (nid < nN) {
            float z = fmaf(dinv[nid], ag[j] + hd[nid], b2[0]);
            out[nid] = 1.f / (1.f + expf(-z));
        }
    }
}

// ================= fallback (small-workspace) atomic path =================

__global__ void deg_kernel(const int* __restrict__ ei, int* __restrict__ deg,
                           const int* __restrict__ flagp, int nE) {
    int i = blockIdx.x * blockDim.x + threadIdx.x;
    if (i >= nE) return;
    int shift = *flagp;
    int d = ei[((size_t)nE << shift) + ((size_t)i << shift)];
    atomicAdd(&deg[d], 1);
}

__global__ void prep_kernel(const int* __restrict__ deg, const float2* __restrict__ x,
                            float* __restrict__ dinv, float2* __restrict__ xd, int nN) {
    int i = blockIdx.x * blockDim.x + threadIdx.x;
    if (i >= nN) return;
    float di = rsqrtf((float)(deg[i] + 1));
    dinv[i] = di;
    float2 v = x[i];
    xd[i] = make_float2(v.x * di, v.y * di);
}

__device__ __forceinline__ void load_edge(const int* __restrict__ ei, int shift,
                                          int nE, int i, int& s, int& d) {
    s = ei[(size_t)i << shift];
    d = ei[((size_t)nE << shift) + ((size_t)i << shift)];
}

__global__ void l1a_kernel(const int* __restrict__ ei, const float2* __restrict__ xd,
                           float* __restrict__ agg, const int* __restrict__ flagp, int nE) {
    int i = blockIdx.x * blockDim.x + threadIdx.x;
    if (i >= nE) return;
    int shift = *flagp;
    int s, d;
    load_edge(ei, shift, nE, i, s, d);
    float2 v = xd[s];
    unsafeAtomicAdd(&agg[(size_t)d * 2], v.x);
    unsafeAtomicAdd(&agg[(size_t)d * 2 + 1], v.y);
}

__global__ void h2f_kernel(const float2* __restrict__ agg, const float2* __restrict__ xd,
                           const float* __restrict__ dinv, const float* __restrict__ W1,
                           const float* __restrict__ b1, const float* __restrict__ W2,
                           float* __restrict__ hd, int nN) {
    int d = blockIdx.x * blockDim.x + threadIdx.x;
    if (d >= nN) return;
    float dd = dinv[d];
    float2 a = agg[d];
    float2 xs = xd[d];
    float ax = (a.x + xs.x * dd) * dd;
    float ay = (a.y + xs.y * dd) * dd;
    float acc = 0.f;
#pragma unroll
    for (int j = 0; j < 8; ++j) {
        float h = fmaf(ax, W1[j], fmaf(ay, W1[8 + j], b1[j]));
        acc = fmaf(fmaxf(h, 0.f), W2[j], acc);
    }
    hd[d] = acc * dd;
}

__global__ void l2a_kernel(const int* __restrict__ ei, const float* __restrict__ hd,
                           float* __restrict__ out2, const int* __restrict__ flagp, int nE) {
    int i = blockIdx.x * blockDim.x + threadIdx.x;
    if (i >= nE) return;
    int shift = *flagp;
    int s, d;
    load_edge(ei, shift, nE, i, s, d);
    unsafeAtomicAdd(&out2[d], hd[s]);
}

__global__ void finf_kernel(const float* __restrict__ out2, const float* __restrict__ hd,
                            const float* __restrict__ dinv, const float* __restrict__ b2,
                            float* __restrict__ out, int nN) {
    int d = blockIdx.x * blockDim.x + threadIdx.x;
    if (d >= nN) return;
    float z = fmaf(dinv[d], out2[d] + hd[d], b2[0]);
    out[d] = 1.f / (1.f + expf(-z));
}

extern "C" void kernel_launch(void* const* d_in, const int* in_sizes, int n_in,
                              void* d_out, int out_size, void* d_ws, size_t ws_size,
                              hipStream_t stream) {
    const float* x  = (const float*)d_in[0];
    const int*   ei = (const int*)d_in[1];
    const float* W1 = (const float*)d_in[2];
    const float* b1 = (const float*)d_in[3];
    const float* W2 = (const float*)d_in[4];
    const float* b2 = (const float*)d_in[5];
    float* out = (float*)d_out;

    const int nE = NE, nN = NN;
    const int bs = 256;
    char* ws = (char*)d_ws;
    const size_t MiB = 1 << 20;

    // bucket-path layout: hist@0 (0.96MiB)  bsum@1MiB  flag@1MiB+64K
    //                     dinv@2MiB  xd@6MiB  hd@14MiB  pairs@18MiB (128MB)
    const size_t csr_need = 18 * MiB + (size_t)nE * 4;

    if (ws_size >= csr_need) {
        int*          hist  = (int*)ws;
        int*          bsum  = (int*)(ws + 1 * MiB);
        int*          flag  = (int*)(ws + 1 * MiB + 65536);
        float*        dinv  = (float*)(ws + 2 * MiB);
        float2*       xd    = (float2*)(ws + 6 * MiB);
        float*        hd    = (float*)(ws + 14 * MiB);
        unsigned int* pairs = (unsigned int*)(ws + 18 * MiB);

        detect_kernel<<<1, 256, 0, stream>>>(ei, flag);
        passA_kernel<<<GAB, 512, 0, stream>>>(ei, hist, flag, nE);
        scan1_kernel<<<NBS, SCAN_B, 0, stream>>>(hist, bsum, NL);
        scan2_kernel<<<1, 1024, 0, stream>>>(bsum, NBS);
        passC_kernel<<<GAB, 512, 0, stream>>>(ei, hist, bsum, pairs, flag, nE);
        passD0_kernel<<<NB, 1024, 0, stream>>>(pairs, hist, bsum, (const float2*)x,
                                               dinv, xd, nE, nN);
        passL1_kernel<<<NB, 1024, 0, stream>>>(pairs, hist, bsum, dinv, xd,
                                               W1, b1, W2, hd, nE, nN);
        passL2_kernel<<<NB, 1024, 0, stream>>>(pairs, hist, bsum, dinv, hd,
                                               b2, out, nE, nN);
    } else {
        // fallback layout: deg@0  agg@4..12  out2@12  dinv@16  xd@20..28  hd@28  flag@32MiB
        int*    deg  = (int*)ws;
        float*  agg  = (float*)(ws + 4 * MiB);
        float*  out2 = (float*)(ws + 12 * MiB);
        float*  dinv = (float*)(ws + 16 * MiB);
        float2* xd   = (float2*)(ws + 20 * MiB);
        float*  hd   = (float*)(ws + 28 * MiB);
        int*    flag = (int*)(ws + 32 * MiB);

        hipMemsetAsync(ws, 0, 16 * MiB, stream);

        detect_kernel<<<1, 256, 0, stream>>>(ei, flag);
        deg_kernel<<<(nE + bs - 1) / bs, bs, 0, stream>>>(ei, deg, flag, nE);
        prep_kernel<<<(nN + bs - 1) / bs, bs, 0, stream>>>(deg, (const float2*)x, dinv, xd, nN);
        l1a_kernel<<<(nE + bs - 1) / bs, bs, 0, stream>>>(ei, xd, agg, flag, nE);
        h2f_kernel<<<(nN + bs - 1) / bs, bs, 0, stream>>>((const float2*)agg, xd, dinv,
                                                          W1, b1, W2, hd, nN);
        l2a_kernel<<<(nE + bs - 1) / bs, bs, 0, stream>>>(ei, hd, out2, flag, nE);
        finf_kernel<<<(nN + bs - 1) / bs, bs, 0, stream>>>(out2, hd, dinv, b2, out, nN);
    }
}

// Round 5
// 1197.466 us; speedup vs baseline: 13.3954x; 1.0947x over previous
//
#include <hip/hip_runtime.h>

#define NN 1000000
#define NE 32000000
#define SCAN_B 256

// bucket decomposition: bucket = d >> 12, 4096 nodes per bucket
#define BK_SH 12
#define BK_SZ 4096
#define NB 245                       // ceil(NN / BK_SZ)
#define GAB 512                      // edge-chunk blocks for passes A and C
#define CHUNK 62500                  // 512 * 62500 = 32,000,000 exactly (div by 4)
#define NL (NB * GAB)                // hist length = 125440 (divisible by 256)
#define NBS (NL / SCAN_B)            // 490 scan blocks (exact)

typedef int vi4 __attribute__((ext_vector_type(4)));

// ---- dtype detector: flag=1 if edge_index is int64, 0 if int32 ----
// int64 little-endian values < 2^31 have all-zero high (odd) words.
__global__ void detect_kernel(const int* __restrict__ ei, int* __restrict__ flag) {
    __shared__ int nz;
    if (threadIdx.x == 0) nz = 0;
    __syncthreads();
    int w = ei[2 * threadIdx.x + 1];
    if (w != 0) atomicAdd(&nz, 1);
    __syncthreads();
    if (threadIdx.x == 0) *flag = (nz == 0) ? 1 : 0;
}

// ---- pass A: per-block LDS histogram over buckets -> hist[b*GAB + g] ----
__global__ void passA_kernel(const int* __restrict__ ei, int* __restrict__ hist,
                             const int* __restrict__ flagp, int nE) {
    __shared__ int h[NB];
    int t = threadIdx.x;
    for (int b = t; b < NB; b += 512) h[b] = 0;
    __syncthreads();
    int shift = *flagp;
    int start = blockIdx.x * CHUNK;
    int end = min(start + CHUNK, nE);
    if (shift == 0) {
        const int* dstp = ei + nE;
        for (int i = start + (t << 2); i < end; i += 2048) {
            vi4 d = __builtin_nontemporal_load((const vi4*)(dstp + i));
            atomicAdd(&h[d.x >> BK_SH], 1);
            atomicAdd(&h[d.y >> BK_SH], 1);
            atomicAdd(&h[d.z >> BK_SH], 1);
            atomicAdd(&h[d.w >> BK_SH], 1);
        }
    } else {
        const int* dstp = ei + ((size_t)nE << 1);
        for (int i = start + t; i < end; i += 512) {
            int d = __builtin_nontemporal_load(dstp + ((size_t)i << 1));
            atomicAdd(&h[d >> BK_SH], 1);
        }
    }
    __syncthreads();
    for (int b = t; b < NB; b += 512)
        hist[(size_t)b * GAB + blockIdx.x] = h[b];
}

// ---- scan stage 1: per-block exclusive scan (in-place), block sums ----
__global__ void scan1_kernel(int* __restrict__ data, int* __restrict__ bsum, int n) {
    __shared__ int sm[SCAN_B];
    int t = threadIdx.x;
    int i = blockIdx.x * SCAN_B + t;
    int v = (i < n) ? data[i] : 0;
    sm[t] = v;
    __syncthreads();
    for (int o = 1; o < SCAN_B; o <<= 1) {
        int a = (t >= o) ? sm[t - o] : 0;
        __syncthreads();
        sm[t] += a;
        __syncthreads();
    }
    if (i < n) data[i] = sm[t] - v;
    if (t == SCAN_B - 1) bsum[blockIdx.x] = sm[t];
}

// ---- scan stage 2: exclusive scan of block sums (1 block, up to 4096) ----
__global__ void scan2_kernel(int* __restrict__ bsum, int nb) {
    __shared__ int sm[1024];
    int t = threadIdx.x;
    int base = t * 4;
    int v[4];
    int s = 0;
#pragma unroll
    for (int j = 0; j < 4; ++j) {
        v[j] = (base + j < nb) ? bsum[base + j] : 0;
        s += v[j];
    }
    sm[t] = s;
    __syncthreads();
    for (int o = 1; o < 1024; o <<= 1) {
        int a = (t >= o) ? sm[t - o] : 0;
        __syncthreads();
        sm[t] += a;
        __syncthreads();
    }
    int run = sm[t] - s;
#pragma unroll
    for (int j = 0; j < 4; ++j) {
        if (base + j < nb) bsum[base + j] = run;
        run += v[j];
    }
}

// ---- pass C: scatter packed edges into bucket-contiguous regions ----
// pairs[idx] = s | (d_local << 20)   (s < 2^20, d_local < 2^12)
__global__ void passC_kernel(const int* __restrict__ ei, const int* __restrict__ hist,
                             const int* __restrict__ bsum, unsigned int* __restrict__ pairs,
                             const int* __restrict__ flagp, int nE) {
    __shared__ int cur[NB];
    int t = threadIdx.x;
    for (int b = t; b < NB; b += 512) {
        int flat = b * GAB + blockIdx.x;
        cur[b] = hist[flat] + bsum[flat >> 8];
    }
    __syncthreads();
    int shift = *flagp;
    int start = blockIdx.x * CHUNK;
    int end = min(start + CHUNK, nE);
    if (shift == 0) {
        const int* srcp = ei;
        const int* dstp = ei + nE;
        for (int i = start + (t << 2); i < end; i += 2048) {
            vi4 s = __builtin_nontemporal_load((const vi4*)(srcp + i));
            vi4 d = __builtin_nontemporal_load((const vi4*)(dstp + i));
            int idx;
            idx = atomicAdd(&cur[d.x >> BK_SH], 1);
            pairs[idx] = (unsigned)s.x | ((unsigned)(d.x & (BK_SZ - 1)) << 20);
            idx = atomicAdd(&cur[d.y >> BK_SH], 1);
            pairs[idx] = (unsigned)s.y | ((unsigned)(d.y & (BK_SZ - 1)) << 20);
            idx = atomicAdd(&cur[d.z >> BK_SH], 1);
            pairs[idx] = (unsigned)s.z | ((unsigned)(d.z & (BK_SZ - 1)) << 20);
            idx = atomicAdd(&cur[d.w >> BK_SH], 1);
            pairs[idx] = (unsigned)s.w | ((unsigned)(d.w & (BK_SZ - 1)) << 20);
        }
    } else {
        for (int i = start + t; i < end; i += 512) {
            int s = __builtin_nontemporal_load(ei + ((size_t)i << 1));
            int d = __builtin_nontemporal_load(ei + ((size_t)nE << 1) + ((size_t)i << 1));
            int idx = atomicAdd(&cur[d >> BK_SH], 1);
            pairs[idx] = (unsigned)s | ((unsigned)(d & (BK_SZ - 1)) << 20);
        }
    }
}

__device__ __forceinline__ void bucket_range(const int* __restrict__ hist,
                                             const int* __restrict__ bsum,
                                             int b, int nE, int& base, int& endp) {
    int f0 = b * GAB;
    base = hist[f0] + bsum[f0 >> 8];
    if (b + 1 < NB) {
        int f1 = (b + 1) * GAB;
        endp = hist[f1] + bsum[f1 >> 8];
    } else {
        endp = nE;
    }
}

// ---- pass D0: per-bucket degree count -> dinv, xd = x * dinv ----
__global__ void passD0_kernel(const unsigned int* __restrict__ pairs,
                              const int* __restrict__ hist, const int* __restrict__ bsum,
                              const float2* __restrict__ x,
                              float* __restrict__ dinv, float2* __restrict__ xd,
                              int nE, int nN) {
    __shared__ int degl[BK_SZ];
    int t = threadIdx.x;
    int b = blockIdx.x;
    for (int j = t; j < BK_SZ; j += 1024) degl[j] = 0;
    __syncthreads();
    int base, endp;
    bucket_range(hist, bsum, b, nE, base, endp);
    for (int k = base + (t << 2); k < endp; k += 4096) {
#pragma unroll
        for (int j = 0; j < 4; ++j)
            if (k + j < endp) {
                unsigned int p = __builtin_nontemporal_load(pairs + k + j);
                atomicAdd(&degl[p >> 20], 1);
            }
    }
    __syncthreads();
    for (int j = t; j < BK_SZ; j += 1024) {
        int nid = (b << BK_SH) + j;
        if (nid < nN) {
            float di = rsqrtf((float)(degl[j] + 1));   // +1 self-loop
            dinv[nid] = di;
            float2 v = x[nid];
            xd[nid] = make_float2(v.x * di, v.y * di);
        }
    }
}

// ---- pass L1: per-bucket aggregate xd, fuse W1/b1/relu/W2 -> hd = h2*dinv ----
__global__ void passL1_kernel(const unsigned int* __restrict__ pairs,
                              const int* __restrict__ hist, const int* __restrict__ bsum,
                              const float* __restrict__ dinv, const float2* __restrict__ xd,
                              const float* __restrict__ W1, const float* __restrict__ b1,
                              const float* __restrict__ W2,
                              float* __restrict__ hd, int nE, int nN) {
    __shared__ float ax[BK_SZ];
    __shared__ float ay[BK_SZ];
    int t = threadIdx.x;
    int b = blockIdx.x;
    for (int j = t; j < BK_SZ; j += 1024) { ax[j] = 0.f; ay[j] = 0.f; }
    __syncthreads();
    int base, endp;
    bucket_range(hist, bsum, b, nE, base, endp);
    for (int k = base + (t << 2); k < endp; k += 4096) {
        unsigned int p[4];
        float2 v[4];
        int lim = min(4, endp - k);
#pragma unroll
        for (int j = 0; j < 4; ++j)
            if (j < lim) p[j] = __builtin_nontemporal_load(pairs + k + j);
#pragma unroll
        for (int j = 0; j < 4; ++j)
            if (j < lim) v[j] = xd[p[j] & 0xFFFFF];
#pragma unroll
        for (int j = 0; j < 4; ++j)
            if (j < lim) {
                int dl = p[j] >> 20;
                atomicAdd(&ax[dl], v[j].x);
                atomicAdd(&ay[dl], v[j].y);
            }
    }
    __syncthreads();
    for (int j = t; j < BK_SZ; j += 1024) {
        int nid = (b << BK_SH) + j;
        if (nid < nN) {
            float dd = dinv[nid];
            float2 xs = xd[nid];
            float AX = (ax[j] + xs.x * dd) * dd;       // self-loop: xd*dd
            float AY = (ay[j] + xs.y * dd) * dd;
            float acc = 0.f;
#pragma unroll
            for (int c = 0; c < 8; ++c) {
                float h = fmaf(AX, W1[c], fmaf(AY, W1[8 + c], b1[c]));
                acc = fmaf(fmaxf(h, 0.f), W2[c], acc);
            }
            hd[nid] = acc * dd;                        // hd = h2 * dinv
        }
    }
}

// ---- pass L2: per-bucket aggregate hd, fuse sigmoid -> out ----
__global__ void passL2_kernel(const unsigned int* __restrict__ pairs,
                              const int* __restrict__ hist, const int* __restrict__ bsum,
                              const float* __restrict__ dinv, const float* __restrict__ hd,
                              const float* __restrict__ b2,
                              float* __restrict__ out, int nE, int nN) {
    __shared__ float ag[BK_SZ];
    int t = threadIdx.x;
    int b = blockIdx.x;
    for (int j = t; j < BK_SZ; j += 1024) ag[j] = 0.f;
    __syncthreads();
    int base, endp;
    bucket_range(hist, bsum, b, nE, base, endp);
    for (int k = base + (t << 2); k < endp; k += 4096) {
        unsigned int p[4];
        float v[4];
        int lim = min(4, endp - k);
#pragma unroll
        for (int j = 0; j < 4; ++j)
            if (j < lim) p[j] = __builtin_nontemporal_load(pairs + k + j);
#pragma unroll
        for (int j = 0; j < 4; ++j)
            if (j < lim) v[j] = hd[p[j] & 0xFFFFF];
#pragma unroll
        for (int j = 0; j < 4; ++j)
            if (j < lim) atomicAdd(&ag[p[j] >> 20], v[j]);
    }
    __syncthreads();
    for (int j = t; j < BK_SZ; j += 1024) {
        int nid = (b << BK_SH) + j;
        if (nid < nN) {
            float z = fmaf(dinv[nid], ag[j] + hd[nid], b2[0]);
            out[nid] = 1.f / (1.f + expf(-z));
        }
    }
}

// ================= fallback (small-workspace) atomic path =================

__global__ void deg_kernel(const int* __restrict__ ei, int* __restrict__ deg,
                           const int* __restrict__ flagp, int nE) {
    int i = blockIdx.x * blockDim.x + threadIdx.x;
    if (i >= nE) return;
    int shift = *flagp;
    int d = ei[((size_t)nE << shift) + ((size_t)i << shift)];
    atomicAdd(&deg[d], 1);
}

__global__ void prep_kernel(const int* __restrict__ deg, const float2* __restrict__ x,
                            float* __restrict__ dinv, float2* __restrict__ xd, int nN) {
    int i = blockIdx.x * blockDim.x + threadIdx.x;
    if (i >= nN) return;
    float di = rsqrtf((float)(deg[i] + 1));
    dinv[i] = di;
    float2 v = x[i];
    xd[i] = make_float2(v.x * di, v.y * di);
}

__device__ __forceinline__ void load_edge(const int* __restrict__ ei, int shift,
                                          int nE, int i, int& s, int& d) {
    s = ei[(size_t)i << shift];
    d = ei[((size_t)nE << shift) + ((size_t)i << shift)];
}

__global__ void l1a_kernel(const int* __restrict__ ei, const float2* __restrict__ xd,
                           float* __restrict__ agg, const int* __restrict__ flagp, int nE) {
    int i = blockIdx.x * blockDim.x + threadIdx.x;
    if (i >= nE) return;
    int shift = *flagp;
    int s, d;
    load_edge(ei, shift, nE, i, s, d);
    float2 v = xd[s];
    unsafeAtomicAdd(&agg[(size_t)d * 2], v.x);
    unsafeAtomicAdd(&agg[(size_t)d * 2 + 1], v.y);
}

__global__ void h2f_kernel(const float2* __restrict__ agg, const float2* __restrict__ xd,
                           const float* __restrict__ dinv, const float* __restrict__ W1,
                           const float* __restrict__ b1, const float* __restrict__ W2,
                           float* __restrict__ hd, int nN) {
    int d = blockIdx.x * blockDim.x + threadIdx.x;
    if (d >= nN) return;
    float dd = dinv[d];
    float2 a = agg[d];
    float2 xs = xd[d];
    float ax = (a.x + xs.x * dd) * dd;
    float ay = (a.y + xs.y * dd) * dd;
    float acc = 0.f;
#pragma unroll
    for (int j = 0; j < 8; ++j) {
        float h = fmaf(ax, W1[j], fmaf(ay, W1[8 + j], b1[j]));
        acc = fmaf(fmaxf(h, 0.f), W2[j], acc);
    }
    hd[d] = acc * dd;
}

__global__ void l2a_kernel(const int* __restrict__ ei, const float* __restrict__ hd,
                           float* __restrict__ out2, const int* __restrict__ flagp, int nE) {
    int i = blockIdx.x * blockDim.x + threadIdx.x;
    if (i >= nE) return;
    int shift = *flagp;
    int s, d;
    load_edge(ei, shift, nE, i, s, d);
    unsafeAtomicAdd(&out2[d], hd[s]);
}

__global__ void finf_kernel(const float* __restrict__ out2, const float* __restrict__ hd,
                            const float* __restrict__ dinv, const float* __restrict__ b2,
                            float* __restrict__ out, int nN) {
    int d = blockIdx.x * blockDim.x + threadIdx.x;
    if (d >= nN) return;
    float z = fmaf(dinv[d], out2[d] + hd[d], b2[0]);
    out[d] = 1.f / (1.f + expf(-z));
}

extern "C" void kernel_launch(void* const* d_in, const int* in_sizes, int n_in,
                              void* d_out, int out_size, void* d_ws, size_t ws_size,
                              hipStream_t stream) {
    const float* x  = (const float*)d_in[0];
    const int*   ei = (const int*)d_in[1];
    const float* W1 = (const float*)d_in[2];
    const float* b1 = (const float*)d_in[3];
    const float* W2 = (const float*)d_in[4];
    const float* b2 = (const float*)d_in[5];
    float* out = (float*)d_out;

    const int nE = NE, nN = NN;
    const int bs = 256;
    char* ws = (char*)d_ws;
    const size_t MiB = 1 << 20;

    // bucket-path layout: hist@0 (0.48MiB)  bsum@1MiB  flag@1MiB+64K
    //                     dinv@2MiB  xd@6MiB  hd@14MiB  pairs@18MiB (128MB)
    const size_t csr_need = 18 * MiB + (size_t)nE * 4;

    if (ws_size >= csr_need) {
        int*          hist  = (int*)ws;
        int*          bsum  = (int*)(ws + 1 * MiB);
        int*          flag  = (int*)(ws + 1 * MiB + 65536);
        float*        dinv  = (float*)(ws + 2 * MiB);
        float2*       xd    = (float2*)(ws + 6 * MiB);
        float*        hd    = (float*)(ws + 14 * MiB);
        unsigned int* pairs = (unsigned int*)(ws + 18 * MiB);

        detect_kernel<<<1, 256, 0, stream>>>(ei, flag);
        passA_kernel<<<GAB, 512, 0, stream>>>(ei, hist, flag, nE);
        scan1_kernel<<<NBS, SCAN_B, 0, stream>>>(hist, bsum, NL);
        scan2_kernel<<<1, 1024, 0, stream>>>(bsum, NBS);
        passC_kernel<<<GAB, 512, 0, stream>>>(ei, hist, bsum, pairs, flag, nE);
        passD0_kernel<<<NB, 1024, 0, stream>>>(pairs, hist, bsum, (const float2*)x,
                                               dinv, xd, nE, nN);
        passL1_kernel<<<NB, 1024, 0, stream>>>(pairs, hist, bsum, dinv, xd,
                                               W1, b1, W2, hd, nE, nN);
        passL2_kernel<<<NB, 1024, 0, stream>>>(pairs, hist, bsum, dinv, hd,
                                               b2, out, nE, nN);
    } else {
        // fallback layout: deg@0  agg@4..12  out2@12  dinv@16  xd@20..28  hd@28  flag@32MiB
        int*    deg  = (int*)ws;
        float*  agg  = (float*)(ws + 4 * MiB);
        float*  out2 = (float*)(ws + 12 * MiB);
        float*  dinv = (float*)(ws + 16 * MiB);
        float2* xd   = (float2*)(ws + 20 * MiB);
        float*  hd   = (float*)(ws + 28 * MiB);
        int*    flag = (int*)(ws + 32 * MiB);

        hipMemsetAsync(ws, 0, 16 * MiB, stream);

        detect_kernel<<<1, 256, 0, stream>>>(ei, flag);
        deg_kernel<<<(nE + bs - 1) / bs, bs, 0, stream>>>(ei, deg, flag, nE);
        prep_kernel<<<(nN + bs - 1) / bs, bs, 0, stream>>>(deg, (const float2*)x, dinv, xd, nN);
        l1a_kernel<<<(nE + bs - 1) / bs, bs, 0, stream>>>(ei, xd, agg, flag, nE);
        h2f_kernel<<<(nN + bs - 1) / bs, bs, 0, stream>>>((const float2*)agg, xd, dinv,
                                                          W1, b1, W2, hd, nN);
        l2a_kernel<<<(nE + bs - 1) / bs, bs, 0, stream>>>(ei, hd, out2, flag, nE);
        finf_kernel<<<(nN + bs - 1) / bs, bs, 0, stream>>>(out2, hd, dinv, b2, out, nN);
    }
}